// Round 1
// baseline (505.978 us; speedup 1.0000x reference)
//
#include <hip/hip_runtime.h>

constexpr int N = 8192;
constexpr int N4 = N / 4;  // float4s per row = 2048

// ---------------- Kernel 1: row sums -> r_inv ----------------
// One block (256 threads) per row. Row = 8192 floats = 2048 float4.
__global__ __launch_bounds__(256) void rowsum_kernel(const float* __restrict__ adj,
                                                     float* __restrict__ r_inv) {
    const int row = blockIdx.x;
    const float4* rowp = reinterpret_cast<const float4*>(adj + (size_t)row * N);
    const int t = threadIdx.x;

    float s = 0.f;
#pragma unroll
    for (int c = 0; c < 8; ++c) {
        float4 v = rowp[c * 256 + t];
        s += (v.x + v.y) + (v.z + v.w);
    }

    // wave (64-lane) butterfly reduce
#pragma unroll
    for (int off = 32; off > 0; off >>= 1)
        s += __shfl_down(s, off, 64);

    __shared__ float ws[4];
    const int lane = t & 63;
    const int wid = t >> 6;
    if (lane == 0) ws[wid] = s;
    __syncthreads();
    if (t == 0) {
        float tot = (ws[0] + ws[1]) + (ws[2] + ws[3]) + 1.0f;  // +1 for identity diag
        float ri = (tot > 0.f) ? rsqrtf(tot) : 0.f;            // inf guard (rowsum==0)
        if (isinf(ri)) ri = 0.f;
        r_inv[row] = ri;
    }
}

// ---------------- Kernel 2: out[i][j] = (adj[i][j] + (i==j)) * r_inv[i] * r_inv[j] ----------------
__global__ __launch_bounds__(256) void scale_kernel(const float* __restrict__ adj,
                                                    const float* __restrict__ r_inv,
                                                    float* __restrict__ out) {
    const int total4 = N * (N / 4);                   // 16,777,216 float4s
    const int stride = gridDim.x * blockDim.x;        // 524,288
    const float4* a4 = reinterpret_cast<const float4*>(adj);
    const float4* r4 = reinterpret_cast<const float4*>(r_inv);
    float4* o4 = reinterpret_cast<float4*>(out);

    for (int f = blockIdx.x * blockDim.x + threadIdx.x; f < total4; f += stride) {
        const int i = f >> 11;        // row (N4 = 2048 = 2^11)
        const int j4 = f & (N4 - 1);  // float4 index within row
        float4 a = a4[f];
        const float ri = r_inv[i];
        const float4 rj = r4[j4];

        // diagonal: add 1 to adj[i][i] before scaling
        const int jbase = j4 << 2;
        if (i >= jbase && i < jbase + 4) {
            reinterpret_cast<float*>(&a)[i - jbase] += 1.0f;
        }

        float4 o;
        o.x = a.x * ri * rj.x;
        o.y = a.y * ri * rj.y;
        o.z = a.z * ri * rj.z;
        o.w = a.w * ri * rj.w;
        o4[f] = o;
    }
}

extern "C" void kernel_launch(void* const* d_in, const int* in_sizes, int n_in,
                              void* d_out, int out_size, void* d_ws, size_t ws_size,
                              hipStream_t stream) {
    const float* adj = (const float*)d_in[0];
    float* out = (float*)d_out;
    float* r_inv = (float*)d_ws;  // 8192 floats = 32 KiB scratch

    rowsum_kernel<<<N, 256, 0, stream>>>(adj, r_inv);
    scale_kernel<<<2048, 256, 0, stream>>>(adj, r_inv, out);
}